// Round 4
// baseline (42.691 us; speedup 1.0000x reference)
//
#include <hip/hip_runtime.h>
#include <math.h>

#define N_ATOMS 2048
#define FLTS_PER_BATCH (N_ATOMS * 3)   // 6144 floats = 1536 float4 = 512 groups

// ws layout:
//   [0..15]                      : int ticket counter (16B reserved, 8B-aligned pad)
//   [16 .. 16+B*40*4)            : part[B*4][10] f32 partials
//   [then]                       : blocksum[16] f64
#define WS_PART_OFF   16
#define NBLK_B        16

// ---------------------------------------------------------------------------
// Kernel A: pure streaming (measured-best structure from round 3, unchanged
// except: na/nb merged into one accumulator -> 10 reduce values; block 0
// zeroes the ticket counter used by kernel B).
// One wave per QUARTER batch (16384 waves). Each lane: 2 groups x 3 float4
// per input = 12 independent loads, fully unrolled. No LDS, no barriers.
// ---------------------------------------------------------------------------
__global__ __launch_bounds__(256) void rmsd_partial_kernel(
    const float* __restrict__ yp, const float* __restrict__ yy,
    float* __restrict__ part /* [B*4][10] */, int* __restrict__ counter)
{
    if (blockIdx.x == 0 && threadIdx.x == 0) *counter = 0;

    const int wid  = (blockIdx.x << 2) + (threadIdx.x >> 6);  // global wave id
    const int lane = threadIdx.x & 63;
    const int b    = wid >> 2;        // batch
    const int q    = wid & 3;         // quarter

    const float4* A  = reinterpret_cast<const float4*>(yp + (size_t)b * FLTS_PER_BATCH);
    const float4* Bv = reinterpret_cast<const float4*>(yy + (size_t)b * FLTS_PER_BATCH);

    float4 av[6], bv[6];
    #pragma unroll
    for (int c = 0; c < 2; ++c) {
        const int g = q * 128 + c * 64 + lane;
        av[3 * c + 0] = A[3 * g + 0];
        av[3 * c + 1] = A[3 * g + 1];
        av[3 * c + 2] = A[3 * g + 2];
        bv[3 * c + 0] = Bv[3 * g + 0];
        bv[3 * c + 1] = Bv[3 * g + 1];
        bv[3 * c + 2] = Bv[3 * g + 2];
    }

    float sxx = 0.f, sxy = 0.f, sxz = 0.f;
    float syx = 0.f, syy = 0.f, syz = 0.f;
    float szx = 0.f, szy = 0.f, szz = 0.f;
    float nrm = 0.f;

    #pragma unroll
    for (int c = 0; c < 2; ++c) {
        const float4 a0 = av[3 * c + 0], a1 = av[3 * c + 1], a2 = av[3 * c + 2];
        const float4 b0 = bv[3 * c + 0], b1 = bv[3 * c + 1], b2 = bv[3 * c + 2];
        float px[4], py[4], pz[4], qx[4], qy[4], qz[4];
        px[0] = a0.x; py[0] = a0.y; pz[0] = a0.z;
        px[1] = a0.w; py[1] = a1.x; pz[1] = a1.y;
        px[2] = a1.z; py[2] = a1.w; pz[2] = a2.x;
        px[3] = a2.y; py[3] = a2.z; pz[3] = a2.w;
        qx[0] = b0.x; qy[0] = b0.y; qz[0] = b0.z;
        qx[1] = b0.w; qy[1] = b1.x; qz[1] = b1.y;
        qx[2] = b1.z; qy[2] = b1.w; qz[2] = b2.x;
        qx[3] = b2.y; qy[3] = b2.z; qz[3] = b2.w;

        #pragma unroll
        for (int k = 0; k < 4; ++k) {
            sxx += px[k] * qx[k]; sxy += px[k] * qy[k]; sxz += px[k] * qz[k];
            syx += py[k] * qx[k]; syy += py[k] * qy[k]; syz += py[k] * qz[k];
            szx += pz[k] * qx[k]; szy += pz[k] * qy[k]; szz += pz[k] * qz[k];
            nrm += px[k] * px[k] + py[k] * py[k] + pz[k] * pz[k]
                 + qx[k] * qx[k] + qy[k] * qy[k] + qz[k] * qz[k];
        }
    }

    float vals[10] = {sxx, sxy, sxz, syx, syy, syz, szx, szy, szz, nrm};
    #pragma unroll
    for (int k = 0; k < 10; ++k) {
        #pragma unroll
        for (int off = 32; off > 0; off >>= 1)
            vals[k] += __shfl_down(vals[k], off, 64);
    }

    if (lane == 0) {
        float* dst = part + (size_t)wid * 10;
        #pragma unroll
        for (int k = 0; k < 10; ++k) dst[k] = vals[k];
    }
}

// ---------------------------------------------------------------------------
// Kernel B: one batch per THREAD (16 blocks x 256). QCP Newton eigen-solve,
// block reduction, then deterministic last-block ticket does the final
// 16-sum (fixed order) + sqrt. No third kernel.
// ---------------------------------------------------------------------------
__global__ __launch_bounds__(256) void rmsd_eigen_kernel(
    const float* __restrict__ part, int* __restrict__ counter,
    double* __restrict__ blocksum, float* __restrict__ out)
{
    const int t = threadIdx.x;
    const int b = blockIdx.x * 256 + t;   // batch index
    const float* P = part + (size_t)b * 40;

    double S[10];
    #pragma unroll
    for (int k = 0; k < 10; ++k)
        S[k] = (double)P[k] + (double)P[10 + k] + (double)P[20 + k] + (double)P[30 + k];

    const double Sxx = S[0], Sxy = S[1], Sxz = S[2];
    const double Syx = S[3], Syy = S[4], Syz = S[5];
    const double Szx = S[6], Szy = S[7], Szz = S[8];
    const double sqn = S[9];

    const double Sxx2 = Sxx * Sxx, Syy2 = Syy * Syy, Szz2 = Szz * Szz;
    const double Sxy2 = Sxy * Sxy, Syz2 = Syz * Syz, Sxz2 = Sxz * Sxz;
    const double Syx2 = Syx * Syx, Szy2 = Szy * Szy, Szx2 = Szx * Szx;

    const double SyzSzymSyySzz2 = 2.0 * (Syz * Szy - Syy * Szz);
    const double Sxx2Syy2Szz2Syz2Szy2 = Syy2 + Szz2 - Sxx2 + Syz2 + Szy2;

    const double C2 = -2.0 * (Sxx2 + Syy2 + Szz2 + Sxy2 + Syx2 + Sxz2 + Szx2 + Syz2 + Szy2);
    const double C1 = 8.0 * (Sxx * Syz * Szy + Syy * Szx * Sxz + Szz * Sxy * Syx -
                             Sxx * Syy * Szz - Syz * Szx * Sxy - Szy * Syx * Sxz);

    const double SxzpSzx = Sxz + Szx;
    const double SyzpSzy = Syz + Szy;
    const double SxypSyx = Sxy + Syx;
    const double SyzmSzy = Syz - Szy;
    const double SxzmSzx = Sxz - Szx;
    const double SxymSyx = Sxy - Syx;
    const double SxxpSyy = Sxx + Syy;
    const double SxxmSyy = Sxx - Syy;
    const double Sxy2Sxz2Syx2Szx2 = Sxy2 + Sxz2 - Syx2 - Szx2;

    const double C0 =
        Sxy2Sxz2Syx2Szx2 * Sxy2Sxz2Syx2Szx2
        + (Sxx2Syy2Szz2Syz2Szy2 + SyzSzymSyySzz2) * (Sxx2Syy2Szz2Syz2Szy2 - SyzSzymSyySzz2)
        + (-(SxzpSzx) * (SyzmSzy) + (SxymSyx) * (SxxmSyy - Szz)) *
          (-(SxzmSzx) * (SyzpSzy) + (SxymSyx) * (SxxmSyy + Szz))
        + (-(SxzpSzx) * (SyzpSzy) - (SxypSyx) * (SxxpSyy - Szz)) *
          (-(SxzmSzx) * (SyzmSzy) - (SxypSyx) * (SxxpSyy + Szz))
        + (+(SxypSyx) * (SyzpSzy) + (SxzpSzx) * (SxxmSyy + Szz)) *
          (-(SxymSyx) * (SyzmSzy) + (SxzpSzx) * (SxxpSyy + Szz))
        + (+(SxypSyx) * (SyzmSzy) + (SxzmSzx) * (SxxmSyy - Szz)) *
          (-(SxymSyx) * (SyzpSzy) + (SxzmSzx) * (SxxpSyy - Szz));

    double lam = 0.5 * sqn;
    for (int i = 0; i < 100; ++i) {
        const double old = lam;
        const double x2 = lam * lam;
        const double bp = (x2 + C2) * lam;
        const double ap = bp + C1;
        const double den = 2.0 * x2 * lam + bp + ap;
        if (den == 0.0) break;
        lam -= (ap * lam + C0) / den;
        if (fabs(lam - old) < fabs(1e-13 * lam)) break;
    }
    double sd = sqn - 2.0 * lam;

    // deterministic block reduction
    #pragma unroll
    for (int off = 32; off > 0; off >>= 1)
        sd += __shfl_down(sd, off, 64);

    __shared__ double red[4];
    __shared__ int ticket_s;
    if ((t & 63) == 0) red[t >> 6] = sd;
    __syncthreads();

    if (t == 0) {
        blocksum[blockIdx.x] = red[0] + red[1] + red[2] + red[3];
        __threadfence();
        ticket_s = atomicAdd(counter, 1);
    }
    __syncthreads();

    // Last-finishing block (any identity) sums all 16 block results in FIXED
    // index order -> bitwise-deterministic output regardless of finish order.
    if (ticket_s == NBLK_B - 1 && t == 0) {
        __threadfence();
        volatile double* bs = blocksum;
        double tot = 0.0;
        #pragma unroll
        for (int i = 0; i < NBLK_B; ++i) tot += bs[i];
        out[0] = (float)sqrt(tot / (double)N_ATOMS);
    }
}

extern "C" void kernel_launch(void* const* d_in, const int* in_sizes, int n_in,
                              void* d_out, int out_size, void* d_ws, size_t ws_size,
                              hipStream_t stream) {
    const float* yp = (const float*)d_in[0];
    const float* yy = (const float*)d_in[1];
    float* out = (float*)d_out;
    const int B = in_sizes[0] / FLTS_PER_BATCH;   // 4096

    int*    counter  = (int*)d_ws;
    float*  part     = (float*)((char*)d_ws + WS_PART_OFF);
    double* blocksum = (double*)((char*)d_ws + WS_PART_OFF + (size_t)B * 40 * sizeof(float));

    rmsd_partial_kernel<<<B, 256, 0, stream>>>(yp, yy, part, counter);
    rmsd_eigen_kernel<<<NBLK_B, 256, 0, stream>>>(part, counter, blocksum, out);
}